// Round 7
// baseline (205.728 us; speedup 1.0000x reference)
//
#include <hip/hip_runtime.h>

#define ALPHA 0.1f
#define NUM_CLASSES 10

typedef __attribute__((ext_vector_type(8))) short bf16x8;
typedef __attribute__((ext_vector_type(4))) float f32x4;

// ---------------------------------------------------------------------------
// ws layout (bytes):  loss @ 0 (4B) | counts @ 4 (400B) | done @ 404 (4B)
// -> zeroed by hipMemsetAsync(512) each launch. Center table is built
//    per-block in LDS (no global prep pass, no prep dispatch).
// ---------------------------------------------------------------------------

__device__ __forceinline__ unsigned pack2(float a, float b) {
    // bf16(a) lo16 | bf16(b) hi16 (truncation -> exact Dekker hi split)
    return (__float_as_uint(b) & 0xFFFF0000u) | (__float_as_uint(a) >> 16);
}
__device__ __forceinline__ float truncbf(float a) {
    return __uint_as_float(__float_as_uint(a) & 0xFFFF0000u);
}

// ---------------------------------------------------------------------------
// dist kernel: 512 threads = 8 INDEPENDENT waves. Wave w owns 32 points
// (t*256 + w*32 ..) x all 256 centers -> swe/swd/argmin finish inside the
// wave (shfl over q); the ONLY barrier is the one-time LDS table staging.
// Center A-frags (Dekker split, MFMA layout) live in 64 KB LDS; ds_read_b128
// contiguous-lane -> conflict-free. amdgpu_waves_per_eu(4,4): occupancy is
// LDS-pinned at 16 waves/CU anyway, so give the allocator the full 128-reg
// budget -- round 6's 64-reg + 8.5 MB scratch spill was the regression.
// Fused finalize via device-scope done counter.
// ---------------------------------------------------------------------------

__global__ __launch_bounds__(512)
__attribute__((amdgpu_waves_per_eu(4, 4)))
void dist_kernel(
    const float* __restrict__ x,
    const int*   __restrict__ y,
    const float* __restrict__ centers,
    float* __restrict__ loss_acc,
    unsigned int* __restrict__ counts,
    unsigned int* __restrict__ done,
    float* __restrict__ out,
    int N, int NT)
{
    extern __shared__ char lds[];
    uint4* tab = (uint4*)lds;                    // [ct16][f4][lane64] uint4
    float* c2s = (float*)(lds + 65536);          // [256]

    const int tid  = threadIdx.x;
    const int w    = tid >> 6;
    const int lane = tid & 63;
    const int q    = lane >> 4;
    const int r    = lane & 15;

    // ---- one-time: build split-bf16 center table + norms in LDS ----
    for (int i = tid; i < 4096; i += 512) {
        const int ct = i >> 8, rem = i & 255, f = rem >> 6, ln = rem & 63;
        const int qq = ln >> 4, rr = ln & 15;
        const float* src = centers + (size_t)(ct * 16 + rr) * 64 + (f & 1) * 32 + qq * 8;
        float4 a = *(const float4*)src;
        float4 b = *(const float4*)(src + 4);
        unsigned w0, w1, w2, w3;
        if (f < 2) {
            w0 = pack2(a.x, a.y); w1 = pack2(a.z, a.w);
            w2 = pack2(b.x, b.y); w3 = pack2(b.z, b.w);
        } else {
            w0 = pack2(a.x - truncbf(a.x), a.y - truncbf(a.y));
            w1 = pack2(a.z - truncbf(a.z), a.w - truncbf(a.w));
            w2 = pack2(b.x - truncbf(b.x), b.y - truncbf(b.y));
            w3 = pack2(b.z - truncbf(b.z), b.w - truncbf(b.w));
        }
        tab[i] = make_uint4(w0, w1, w2, w3);
    }
    if (tid < 256) {
        const float4* crow = (const float4*)(centers + (size_t)tid * 64);
        float s = 0.f;
#pragma unroll
        for (int j = 0; j < 16; ++j) {
            float4 v = crow[j];
            s = fmaf(v.x, v.x, s); s = fmaf(v.y, v.y, s);
            s = fmaf(v.z, v.z, s); s = fmaf(v.w, v.w, s);
        }
        c2s[tid] = s;
    }
    __syncthreads();   // the only barrier

    float loss_local = 0.f;

    for (int t = blockIdx.x; t < NT; t += gridDim.x) {
        const int base = t * 256 + w * 32;    // this wave's 32 points

        // ---- convert 32 points (2 subtiles) to split-bf16 B-frags ----
        bf16x8 bh0[2], bh1[2], bl0[2], bl1[2];
        float x2p[2];
#pragma unroll
        for (int s = 0; s < 2; ++s) {
            const int row = base + s * 16 + r;
            const float4* X = (const float4*)(x + (size_t)row * 64);
            float4 v0 = X[q * 2], v1 = X[q * 2 + 1];       // k = q*8..
            float4 v2 = X[8 + q * 2], v3 = X[9 + q * 2];   // k = 32+q*8..

            float p = v0.x * v0.x;
            p = fmaf(v0.y, v0.y, p); p = fmaf(v0.z, v0.z, p); p = fmaf(v0.w, v0.w, p);
            p = fmaf(v1.x, v1.x, p); p = fmaf(v1.y, v1.y, p); p = fmaf(v1.z, v1.z, p); p = fmaf(v1.w, v1.w, p);
            p = fmaf(v2.x, v2.x, p); p = fmaf(v2.y, v2.y, p); p = fmaf(v2.z, v2.z, p); p = fmaf(v2.w, v2.w, p);
            p = fmaf(v3.x, v3.x, p); p = fmaf(v3.y, v3.y, p); p = fmaf(v3.z, v3.z, p); p = fmaf(v3.w, v3.w, p);
            p += __shfl_xor(p, 16);
            p += __shfl_xor(p, 32);   // all lanes: ||x_{s*16+r}||^2
            x2p[s] = p;

            union { bf16x8 v; unsigned u[4]; } h0, h1, l0, l1;
            h0.u[0] = pack2(v0.x, v0.y); h0.u[1] = pack2(v0.z, v0.w);
            h0.u[2] = pack2(v1.x, v1.y); h0.u[3] = pack2(v1.z, v1.w);
            h1.u[0] = pack2(v2.x, v2.y); h1.u[1] = pack2(v2.z, v2.w);
            h1.u[2] = pack2(v3.x, v3.y); h1.u[3] = pack2(v3.z, v3.w);
            l0.u[0] = pack2(v0.x - truncbf(v0.x), v0.y - truncbf(v0.y));
            l0.u[1] = pack2(v0.z - truncbf(v0.z), v0.w - truncbf(v0.w));
            l0.u[2] = pack2(v1.x - truncbf(v1.x), v1.y - truncbf(v1.y));
            l0.u[3] = pack2(v1.z - truncbf(v1.z), v1.w - truncbf(v1.w));
            l1.u[0] = pack2(v2.x - truncbf(v2.x), v2.y - truncbf(v2.y));
            l1.u[1] = pack2(v2.z - truncbf(v2.z), v2.w - truncbf(v2.w));
            l1.u[2] = pack2(v3.x - truncbf(v3.x), v3.y - truncbf(v3.y));
            l1.u[3] = pack2(v3.z - truncbf(v3.z), v3.w - truncbf(v3.w));
            bh0[s] = h0.v; bh1[s] = h1.v; bl0[s] = l0.v; bl1[s] = l1.v;
        }

        float swe[2] = {0.f, 0.f}, swd[2] = {0.f, 0.f};
        unsigned best[2] = {0xFFFFFFFFu, 0xFFFFFFFFu};

#pragma unroll 1
        for (int ct = 0; ct < 16; ++ct) {
            union { uint4 u; bf16x8 v; } af0, af1, af2, af3;
            af0.u = tab[(ct * 4 + 0) * 64 + lane];
            af1.u = tab[(ct * 4 + 1) * 64 + lane];
            af2.u = tab[(ct * 4 + 2) * 64 + lane];
            af3.u = tab[(ct * 4 + 3) * 64 + lane];
            const float4 c2v = *(const float4*)(c2s + ct * 16 + q * 4);

            // two independent MFMA chains (s=0, s=1) for ILP
            f32x4 a0 = (f32x4){0.f, 0.f, 0.f, 0.f};
            f32x4 a1 = (f32x4){0.f, 0.f, 0.f, 0.f};
            a0 = __builtin_amdgcn_mfma_f32_16x16x32_bf16(af0.v, bh0[0], a0, 0, 0, 0); // ch.xh
            a1 = __builtin_amdgcn_mfma_f32_16x16x32_bf16(af0.v, bh0[1], a1, 0, 0, 0);
            a0 = __builtin_amdgcn_mfma_f32_16x16x32_bf16(af1.v, bh1[0], a0, 0, 0, 0);
            a1 = __builtin_amdgcn_mfma_f32_16x16x32_bf16(af1.v, bh1[1], a1, 0, 0, 0);
            a0 = __builtin_amdgcn_mfma_f32_16x16x32_bf16(af2.v, bh0[0], a0, 0, 0, 0); // cl.xh
            a1 = __builtin_amdgcn_mfma_f32_16x16x32_bf16(af2.v, bh0[1], a1, 0, 0, 0);
            a0 = __builtin_amdgcn_mfma_f32_16x16x32_bf16(af3.v, bh1[0], a0, 0, 0, 0);
            a1 = __builtin_amdgcn_mfma_f32_16x16x32_bf16(af3.v, bh1[1], a1, 0, 0, 0);
            a0 = __builtin_amdgcn_mfma_f32_16x16x32_bf16(af0.v, bl0[0], a0, 0, 0, 0); // ch.xl
            a1 = __builtin_amdgcn_mfma_f32_16x16x32_bf16(af0.v, bl0[1], a1, 0, 0, 0);
            a0 = __builtin_amdgcn_mfma_f32_16x16x32_bf16(af1.v, bl1[0], a0, 0, 0, 0);
            a1 = __builtin_amdgcn_mfma_f32_16x16x32_bf16(af1.v, bl1[1], a1, 0, 0, 0);

            const float c2a[4] = {c2v.x, c2v.y, c2v.z, c2v.w};
#pragma unroll
            for (int reg = 0; reg < 4; ++reg) {
                const unsigned kid = (unsigned)(ct * 16 + q * 4 + reg);
                {
                    float d = fmaf(-2.f, a0[reg], x2p[0] + c2a[reg]);
                    d = fmaxf(d, 0.f);
                    best[0] = min(best[0], (__float_as_uint(d) & 0xFFFFFF00u) | kid);
                    float wg = exp2f(-ALPHA * __log2f(1.f + d));
                    swe[0] += wg;
                    swd[0] = fmaf(wg, d, swd[0]);
                }
                {
                    float d = fmaf(-2.f, a1[reg], x2p[1] + c2a[reg]);
                    d = fmaxf(d, 0.f);
                    best[1] = min(best[1], (__float_as_uint(d) & 0xFFFFFF00u) | kid);
                    float wg = exp2f(-ALPHA * __log2f(1.f + d));
                    swe[1] += wg;
                    swd[1] = fmaf(wg, d, swd[1]);
                }
            }
        }

        // ---- per-point finish (reduce over the 4 q-lanes of col r) ----
#pragma unroll
        for (int s = 0; s < 2; ++s) {
            float SWE = swe[s], SWD = swd[s];
            unsigned B = best[s];
            SWE += __shfl_xor(SWE, 16); SWE += __shfl_xor(SWE, 32);
            SWD += __shfl_xor(SWD, 16); SWD += __shfl_xor(SWD, 32);
            B = min(B, (unsigned)__shfl_xor((int)B, 16));
            B = min(B, (unsigned)__shfl_xor((int)B, 32));
            if (q == 0) {
                loss_local += SWD / SWE;
                const unsigned bk = B & 0xFFu;
                if (bk < NUM_CLASSES) {
                    const int lbl = y[base + s * 16 + r];
                    atomicAdd(&counts[bk * NUM_CLASSES + lbl], 1u);
                }
            }
        }
    }

    // ---- loss: wave-local reduce, one atomic per wave ----
    float v = loss_local;
#pragma unroll
    for (int o = 32; o > 0; o >>= 1) v += __shfl_down(v, o);
    if (lane == 0) atomicAdd(loss_acc, v);

    // ---- fused finalize: last block does the greedy assignment ----
    __syncthreads();
    if (tid == 0) {
        __threadfence();
        if (atomicAdd(done, 1u) == gridDim.x - 1) {
            __threadfence();
            float c[NUM_CLASSES][NUM_CLASSES];
            for (int i = 0; i < NUM_CLASSES; ++i)
                for (int j = 0; j < NUM_CLASSES; ++j)
                    c[i][j] = (float)atomicAdd(&counts[i * NUM_CLASSES + j], 0u);
            const float L = atomicAdd(loss_acc, 0.f);

            bool used[NUM_CLASSES];
            for (int i = 0; i < NUM_CLASSES; ++i) used[i] = false;
            float correct = 0.f;
            for (int i = 0; i < NUM_CLASSES; ++i) {
                float rowsum = 0.f;
                for (int j = 0; j < NUM_CLASSES; ++j) rowsum += c[i][j];
                const bool has_points = rowsum > 0.f;

                int label = 0;
                float mx = c[i][0];
                for (int j = 1; j < NUM_CLASSES; ++j)
                    if (c[i][j] > mx) { mx = c[i][j]; label = j; }

                if (used[label]) {
                    float mm = used[0] ? 0.f : c[i][0];
                    int l2 = 0;
                    for (int j = 1; j < NUM_CLASSES; ++j) {
                        float vv = used[j] ? 0.f : c[i][j];
                        if (vv > mm) { mm = vv; l2 = j; }
                    }
                    label = l2;
                }
                if (has_points) {
                    correct += c[i][label];
                    used[label] = true;
                }
            }
            out[0] = L;
            out[1] = correct / (float)N;
        }
    }
}

// ---------------------------------------------------------------------------

extern "C" void kernel_launch(void* const* d_in, const int* in_sizes, int n_in,
                              void* d_out, int out_size, void* d_ws, size_t ws_size,
                              hipStream_t stream)
{
    const float* x       = (const float*)d_in[0];
    const int*   y       = (const int*)d_in[1];
    const float* centers = (const float*)d_in[2];
    float* out = (float*)d_out;

    const int N  = in_sizes[0] / 64;  // D = 64
    const int NT = N / 256;           // 256-point block tiles (8 waves x 32)

    float* loss          = (float*)d_ws;
    unsigned int* counts = (unsigned int*)((char*)d_ws + 4);
    unsigned int* done   = (unsigned int*)((char*)d_ws + 404);

    static const size_t SMEM = 66560;
    static int once = [] {
        hipFuncSetAttribute((const void*)dist_kernel,
                            hipFuncAttributeMaxDynamicSharedMemorySize, (int)SMEM);
        return 0;
    }();
    (void)once;

    hipMemsetAsync(d_ws, 0, 512, stream);

    int grid = 512;                    // 2 blocks/CU resident
    if (grid > NT) grid = NT;
    dist_kernel<<<grid, 512, SMEM, stream>>>(x, y, centers, loss, counts,
                                             done, out, N, NT);
}